// Round 2
// baseline (489.116 us; speedup 1.0000x reference)
//
#include <hip/hip_runtime.h>
#include <stdint.h>

// B=4, S=4096, HID=1024, H=8, D=128, CHUNK=64, NC=64 chunks, BH=B*H=32
typedef __bf16 bf16x8 __attribute__((ext_vector_type(8)));
typedef float  f32x4  __attribute__((ext_vector_type(4)));

static __device__ __forceinline__ void gload16(const void* g, void* l) {
  __builtin_amdgcn_global_load_lds((__attribute__((address_space(1))) void*)g,
                                   (__attribute__((address_space(3))) void*)l,
                                   16, 0, 0);
}

static __device__ __forceinline__ f32x4 mfma16(bf16x8 a, bf16x8 b, f32x4 c) {
  return __builtin_amdgcn_mfma_f32_16x16x32_bf16(a, b, c, 0, 0, 0);
}

// ---------------- casts ----------------
__global__ __launch_bounds__(256) void cast8_k(const float* __restrict__ in,
                                               __bf16* __restrict__ out) {
  const size_t i = ((size_t)blockIdx.x * 256 + threadIdx.x) * 8;
  const float4 v0 = *(const float4*)(in + i);
  const float4 v1 = *(const float4*)(in + i + 4);
  bf16x8 o;
  o[0] = (__bf16)v0.x; o[1] = (__bf16)v0.y; o[2] = (__bf16)v0.z; o[3] = (__bf16)v0.w;
  o[4] = (__bf16)v1.x; o[5] = (__bf16)v1.y; o[6] = (__bf16)v1.z; o[7] = (__bf16)v1.w;
  *(bf16x8*)(out + i) = o;
}

__global__ __launch_bounds__(256) void castw_k(const float* __restrict__ w0, const float* __restrict__ w1,
                                               const float* __restrict__ w2, const float* __restrict__ w3,
                                               __bf16* __restrict__ o0, __bf16* __restrict__ o1,
                                               __bf16* __restrict__ o2, __bf16* __restrict__ o3) {
  const float* in; __bf16* out;
  switch (blockIdx.y) {
    case 0: in = w0; out = o0; break;
    case 1: in = w1; out = o1; break;
    case 2: in = w2; out = o2; break;
    default: in = w3; out = o3; break;
  }
  const size_t i = ((size_t)blockIdx.x * 256 + threadIdx.x) * 8;
  const float4 v0 = *(const float4*)(in + i);
  const float4 v1 = *(const float4*)(in + i + 4);
  bf16x8 o;
  o[0] = (__bf16)v0.x; o[1] = (__bf16)v0.y; o[2] = (__bf16)v0.z; o[3] = (__bf16)v0.w;
  o[4] = (__bf16)v1.x; o[5] = (__bf16)v1.y; o[6] = (__bf16)v1.z; o[7] = (__bf16)v1.w;
  *(bf16x8*)(out + i) = o;
}

// ---------------- QKV GEMM (C = A @ W^T), 128x128 tile, BK=32 ----------------
// z=0 -> Q rows; z=1 -> K rows + Kt[bh][d][s]; z=2 -> Vt[bh][e][s]
__global__ __launch_bounds__(256)
void gemm_qkv_k(const __bf16* __restrict__ A,
                const __bf16* __restrict__ Bq, const __bf16* __restrict__ Bk, const __bf16* __restrict__ Bv,
                __bf16* __restrict__ Qo, __bf16* __restrict__ Ko,
                __bf16* __restrict__ Kt, __bf16* __restrict__ Vt) {
  alignas(16) __shared__ __bf16 As[128 * 32];
  alignas(16) __shared__ __bf16 Bs[128 * 32];
  const int tid = threadIdx.x;
  const int z = blockIdx.z;
  const __bf16* W = (z == 0) ? Bq : (z == 1) ? Bk : Bv;
  const int m0 = blockIdx.y * 128;
  const int n0 = blockIdx.x * 128;
  const int l = tid & 63, w = tid >> 6;
  const int wr = (w >> 1) * 64, wc = (w & 1) * 64;
  const int lr = l & 15, lk = (l >> 4) * 8;
  const int srow = tid >> 2, scol = (tid & 3) * 8;

  f32x4 acc[4][4] = {};
  for (int k0 = 0; k0 < 1024; k0 += 32) {
    gload16(A + (size_t)(m0 + srow) * 1024 + k0 + scol, &As[srow * 32 + scol]);
    gload16(A + (size_t)(m0 + 64 + srow) * 1024 + k0 + scol, &As[(64 + srow) * 32 + scol]);
    gload16(W + (size_t)(n0 + srow) * 1024 + k0 + scol, &Bs[srow * 32 + scol]);
    gload16(W + (size_t)(n0 + 64 + srow) * 1024 + k0 + scol, &Bs[(64 + srow) * 32 + scol]);
    __syncthreads();
    bf16x8 af[4], bfr[4];
#pragma unroll
    for (int mt = 0; mt < 4; ++mt) af[mt] = *(const bf16x8*)&As[(wr + mt * 16 + lr) * 32 + lk];
#pragma unroll
    for (int nt = 0; nt < 4; ++nt) bfr[nt] = *(const bf16x8*)&Bs[(wc + nt * 16 + lr) * 32 + lk];
#pragma unroll
    for (int mt = 0; mt < 4; ++mt)
#pragma unroll
      for (int nt = 0; nt < 4; ++nt)
        acc[mt][nt] = mfma16(af[mt], bfr[nt], acc[mt][nt]);
    __syncthreads();
  }
#pragma unroll
  for (int mt = 0; mt < 4; ++mt)
#pragma unroll
    for (int r = 0; r < 4; ++r) {
      const int m = m0 + wr + mt * 16 + (l >> 4) * 4 + r;
#pragma unroll
      for (int nt = 0; nt < 4; ++nt) {
        const int n = n0 + wc + nt * 16 + lr;
        const __bf16 v = (__bf16)acc[mt][nt][r];
        if (z == 0) {
          Qo[(size_t)m * 1024 + n] = v;
        } else {
          const int bb = m >> 12, s = m & 4095, hh = n >> 7, dd = n & 127;
          if (z == 1) {
            Ko[(size_t)m * 1024 + n] = v;
            Kt[((size_t)((bb * 8 + hh) * 128 + dd)) * 4096 + s] = v;
          } else {
            Vt[((size_t)((bb * 8 + hh) * 128 + dd)) * 4096 + s] = v;
          }
        }
      }
    }
}

// ---------------- output GEMM (f32 out) ----------------
__global__ __launch_bounds__(256)
void gemm_out_k(const __bf16* __restrict__ A, const __bf16* __restrict__ W,
                float* __restrict__ Co) {
  alignas(16) __shared__ __bf16 As[128 * 32];
  alignas(16) __shared__ __bf16 Bs[128 * 32];
  const int tid = threadIdx.x;
  const int m0 = blockIdx.y * 128;
  const int n0 = blockIdx.x * 128;
  const int l = tid & 63, w = tid >> 6;
  const int wr = (w >> 1) * 64, wc = (w & 1) * 64;
  const int lr = l & 15, lk = (l >> 4) * 8;
  const int srow = tid >> 2, scol = (tid & 3) * 8;

  f32x4 acc[4][4] = {};
  for (int k0 = 0; k0 < 1024; k0 += 32) {
    gload16(A + (size_t)(m0 + srow) * 1024 + k0 + scol, &As[srow * 32 + scol]);
    gload16(A + (size_t)(m0 + 64 + srow) * 1024 + k0 + scol, &As[(64 + srow) * 32 + scol]);
    gload16(W + (size_t)(n0 + srow) * 1024 + k0 + scol, &Bs[srow * 32 + scol]);
    gload16(W + (size_t)(n0 + 64 + srow) * 1024 + k0 + scol, &Bs[(64 + srow) * 32 + scol]);
    __syncthreads();
    bf16x8 af[4], bfr[4];
#pragma unroll
    for (int mt = 0; mt < 4; ++mt) af[mt] = *(const bf16x8*)&As[(wr + mt * 16 + lr) * 32 + lk];
#pragma unroll
    for (int nt = 0; nt < 4; ++nt) bfr[nt] = *(const bf16x8*)&Bs[(wc + nt * 16 + lr) * 32 + lk];
#pragma unroll
    for (int mt = 0; mt < 4; ++mt)
#pragma unroll
      for (int nt = 0; nt < 4; ++nt)
        acc[mt][nt] = mfma16(af[mt], bfr[nt], acc[mt][nt]);
    __syncthreads();
  }
#pragma unroll
  for (int mt = 0; mt < 4; ++mt)
#pragma unroll
    for (int r = 0; r < 4; ++r) {
      const int m = m0 + wr + mt * 16 + (l >> 4) * 4 + r;
#pragma unroll
      for (int nt = 0; nt < 4; ++nt) {
        const int n = n0 + wc + nt * 16 + lr;
        Co[(size_t)m * 1024 + n] = acc[mt][nt][r];
      }
    }
}

// ---------------- z chunk sums: zc[bh][c][d] = sum_t K[c*64+t][d] ----------------
__global__ __launch_bounds__(128)
void z1_k(const __bf16* __restrict__ K, float* __restrict__ zc) {
  const int c = blockIdx.x, bh = blockIdx.y;
  const int bb = bh >> 3, hh = bh & 7;
  const int d = threadIdx.x;
  float a = 0.0f;
  for (int t = 0; t < 64; ++t)
    a += (float)K[((size_t)(bb * 4096 + c * 64 + t)) * 1024 + hh * 128 + d];
  zc[(size_t)(bh * 64 + c) * 128 + d] = a;
}

// in-place exclusive prefix of zc over chunks
__global__ __launch_bounds__(128)
void z2_k(float* __restrict__ zc) {
  const int bh = blockIdx.x;
  const int d = threadIdx.x;
  float run = 0.0f;
  for (int cc = 0; cc < 64; ++cc) {
    float* p = zc + (size_t)(bh * 64 + cc) * 128 + d;
    const float old = *p;
    *p = run;
    run += old;
  }
}

// ---------------- pass A: per-chunk S_T[e][d] = sum_t V[t,e]*K[t,d] ----------------
__global__ __launch_bounds__(256)
void passA_k(const __bf16* __restrict__ Kt, const __bf16* __restrict__ Vt,
             __bf16* __restrict__ Sc) {
  const int c = blockIdx.x, bh = blockIdx.y;
  const int tid = threadIdx.x, l = tid & 63, w = tid >> 6;
  const int wr = (w >> 1) * 64, wc = (w & 1) * 64;
  const int lr = l & 15, lk = (l >> 4) * 8;
  f32x4 acc[4][4] = {};
#pragma unroll
  for (int kk = 0; kk < 2; ++kk) {
    const int t = c * 64 + kk * 32 + lk;
    bf16x8 av[4], bk[4];
#pragma unroll
    for (int mt = 0; mt < 4; ++mt)
      av[mt] = *(const bf16x8*)(Vt + ((size_t)(bh * 128 + wr + mt * 16 + lr)) * 4096 + t);
#pragma unroll
    for (int nt = 0; nt < 4; ++nt)
      bk[nt] = *(const bf16x8*)(Kt + ((size_t)(bh * 128 + wc + nt * 16 + lr)) * 4096 + t);
#pragma unroll
    for (int mt = 0; mt < 4; ++mt)
#pragma unroll
      for (int nt = 0; nt < 4; ++nt)
        acc[mt][nt] = mfma16(av[mt], bk[nt], acc[mt][nt]);
  }
  const size_t sbase = ((size_t)(bh * 64 + c)) << 14;
#pragma unroll
  for (int mt = 0; mt < 4; ++mt)
#pragma unroll
    for (int r = 0; r < 4; ++r) {
      const int e = wr + mt * 16 + (l >> 4) * 4 + r;
#pragma unroll
      for (int nt = 0; nt < 4; ++nt) {
        const int d = wc + nt * 16 + lr;
        Sc[sbase + (size_t)e * 128 + d] = (__bf16)acc[mt][nt][r];
      }
    }
}

// ---------------- pass B: in-place exclusive prefix of Sc over chunks ----------------
__global__ __launch_bounds__(256)
void passB_k(__bf16* __restrict__ Sc) {
  const int bh = blockIdx.y;
  const int idx = blockIdx.x * 256 + threadIdx.x;
  float run = 0.0f;
  for (int cc = 0; cc < 64; ++cc) {
    __bf16* p = Sc + (((size_t)(bh * 64 + cc)) << 14) + idx;
    const float old = (float)*p;
    *p = (__bf16)run;
    run += old;
  }
}

// ---------------- pass C: outputs + denom + rmsnorm ----------------
__global__ __launch_bounds__(256)
void passC_k(const __bf16* __restrict__ Q, const __bf16* __restrict__ K,
             const __bf16* __restrict__ Vt, const __bf16* __restrict__ Sp,
             const float* __restrict__ zp, const float* __restrict__ nw,
             __bf16* __restrict__ O) {
  alignas(16) __shared__ __bf16 ScL[64 * 72];
  alignas(16) __shared__ float OL[64 * 132];
  alignas(16) __shared__ float zPL[128];
  alignas(16) __shared__ float nwL[128];
  alignas(16) __shared__ float dnL[64];
  const int c = blockIdx.x, bh = blockIdx.y;
  const int bb = bh >> 3, hh = bh & 7;
  const int tid = threadIdx.x, l = tid & 63, wv = tid >> 6;
  const int lr = l & 15, lk = (l >> 4) * 8;
  if (tid < 128) zPL[tid] = zp[(size_t)(bh * 64 + c) * 128 + tid];
  else nwL[tid - 128] = nw[tid - 128];

  const size_t qbase = ((size_t)(bb * 4096 + c * 64)) * 1024 + hh * 128;
  const size_t sbase = ((size_t)(bh * 64 + c)) << 14;

  f32x4 accO[4][2] = {};
  f32x4 accS[4] = {};
#pragma unroll
  for (int kk = 0; kk < 4; ++kk) {
    const int dof = kk * 32 + lk;
    bf16x8 aQ[4], bS[2], bK;
#pragma unroll
    for (int mt = 0; mt < 4; ++mt)
      aQ[mt] = *(const bf16x8*)(Q + qbase + (size_t)(mt * 16 + lr) * 1024 + dof);
#pragma unroll
    for (int nt = 0; nt < 2; ++nt)
      bS[nt] = *(const bf16x8*)(Sp + sbase + (size_t)(wv * 32 + nt * 16 + lr) * 128 + dof);
    bK = *(const bf16x8*)(K + qbase + (size_t)(wv * 16 + lr) * 1024 + dof);
#pragma unroll
    for (int mt = 0; mt < 4; ++mt) {
      accS[mt] = mfma16(aQ[mt], bK, accS[mt]);
#pragma unroll
      for (int nt = 0; nt < 2; ++nt)
        accO[mt][nt] = mfma16(aQ[mt], bS[nt], accO[mt][nt]);
    }
  }
  // masked scores -> LDS (bf16)
#pragma unroll
  for (int mt = 0; mt < 4; ++mt)
#pragma unroll
    for (int r = 0; r < 4; ++r) {
      const int srow = mt * 16 + (l >> 4) * 4 + r;
      const int tcol = wv * 16 + lr;
      ScL[srow * 72 + tcol] = (__bf16)((tcol <= srow) ? accS[mt][r] : 0.0f);
    }
  __syncthreads();
  // intra: acc += scores @ V   (B-operand = Vt rows)
#pragma unroll
  for (int kk2 = 0; kk2 < 2; ++kk2) {
    const int tof = kk2 * 32 + lk;
    bf16x8 aS[4], bV[2];
#pragma unroll
    for (int mt = 0; mt < 4; ++mt) aS[mt] = *(const bf16x8*)&ScL[(mt * 16 + lr) * 72 + tof];
#pragma unroll
    for (int nt = 0; nt < 2; ++nt)
      bV[nt] = *(const bf16x8*)(Vt + ((size_t)(bh * 128 + wv * 32 + nt * 16 + lr)) * 4096 + c * 64 + tof);
#pragma unroll
    for (int mt = 0; mt < 4; ++mt)
#pragma unroll
      for (int nt = 0; nt < 2; ++nt)
        accO[mt][nt] = mfma16(aS[mt], bV[nt], accO[mt][nt]);
  }
  // denom[s] = max(|q.z_prev + rowsum(masked scores)|, 1)
  if (tid < 64) {
    float rs = 0.0f;
    for (int t = 0; t < 64; ++t) rs += (float)ScL[tid * 72 + t];
    float qz = 0.0f;
    const __bf16* qrow = Q + qbase + (size_t)tid * 1024;
#pragma unroll
    for (int j = 0; j < 16; ++j) {
      const bf16x8 q8 = *(const bf16x8*)(qrow + j * 8);
#pragma unroll
      for (int i = 0; i < 8; ++i) qz += (float)q8[i] * zPL[j * 8 + i];
    }
    dnL[tid] = fmaxf(fabsf(qz + rs), 1.0f);
  }
  __syncthreads();
#pragma unroll
  for (int mt = 0; mt < 4; ++mt)
#pragma unroll
    for (int r = 0; r < 4; ++r) {
      const int row = mt * 16 + (l >> 4) * 4 + r;
#pragma unroll
      for (int nt = 0; nt < 2; ++nt) {
        const int col = wv * 32 + nt * 16 + lr;
        OL[row * 132 + col] = accO[mt][nt][r] / dnL[row];
      }
    }
  __syncthreads();
  // rmsnorm over D=128 + store bf16
  const int s = tid >> 2, e0 = (tid & 3) * 32;
  float ss = 0.0f;
  for (int i = 0; i < 32; ++i) { const float v = OL[s * 132 + e0 + i]; ss += v * v; }
  ss += __shfl_xor(ss, 1);
  ss += __shfl_xor(ss, 2);
  const float scale = rsqrtf(ss * (1.0f / 128.0f) + 1e-5f);
  __bf16* orow = O + qbase + (size_t)s * 1024 + e0;
#pragma unroll
  for (int i8 = 0; i8 < 4; ++i8) {
    bf16x8 ov;
#pragma unroll
    for (int j = 0; j < 8; ++j) {
      const int e = e0 + i8 * 8 + j;
      ov[j] = (__bf16)(OL[s * 132 + e] * scale * nwL[e]);
    }
    *(bf16x8*)(orow + i8 * 8) = ov;
  }
}

extern "C" void kernel_launch(void* const* d_in, const int* in_sizes, int n_in,
                              void* d_out, int out_size, void* d_ws, size_t ws_size,
                              hipStream_t stream) {
  (void)in_sizes; (void)n_in; (void)out_size; (void)ws_size;
  const float* hid = (const float*)d_in[0];
  const float* Wq  = (const float*)d_in[1];
  const float* Wk  = (const float*)d_in[2];
  const float* Wv  = (const float*)d_in[3];
  const float* Wo  = (const float*)d_in[4];
  const float* nw  = (const float*)d_in[5];

  char* ws = (char*)d_ws;
  size_t off = 0;
  auto nxt = [&](size_t bytes) -> char* {
    char* p = ws + off;
    off += (bytes + 255) & ~(size_t)255;
    return p;
  };
  __bf16* hA  = (__bf16*)nxt(33554432);   // hidden bf16 [16384][1024]; reused as Ob after gemm_qkv
  __bf16* wqB = (__bf16*)nxt(2097152);
  __bf16* wkB = (__bf16*)nxt(2097152);
  __bf16* wvB = (__bf16*)nxt(2097152);
  __bf16* woB = (__bf16*)nxt(2097152);
  __bf16* Qb  = (__bf16*)nxt(33554432);   // Q rows [16384][1024]
  __bf16* Kb  = (__bf16*)nxt(33554432);   // K rows
  __bf16* Ktb = (__bf16*)nxt(33554432);   // K^T [bh][d][s]
  __bf16* Vtb = (__bf16*)nxt(33554432);   // V^T [bh][e][s]
  __bf16* Scb = (__bf16*)nxt(67108864);   // chunk states -> exclusive prefix [bh][c][e][d]
  float*  zcb = (float*)nxt(1048576);     // chunk z sums -> exclusive prefix [bh][c][d]
  __bf16* Ob  = hA;                       // alias: hA dead after gemm_qkv_k (ws stays < 256 MiB)

  cast8_k<<<8192, 256, 0, stream>>>(hid, hA);
  castw_k<<<dim3(512, 4), 256, 0, stream>>>(Wq, Wk, Wv, Wo, wqB, wkB, wvB, woB);
  gemm_qkv_k<<<dim3(8, 128, 3), 256, 0, stream>>>(hA, wqB, wkB, wvB, Qb, Kb, Ktb, Vtb);
  z1_k<<<dim3(64, 32), 128, 0, stream>>>(Kb, zcb);
  passA_k<<<dim3(64, 32), 256, 0, stream>>>(Ktb, Vtb, Scb);
  passB_k<<<dim3(64, 32), 256, 0, stream>>>(Scb);
  z2_k<<<32, 128, 0, stream>>>(zcb);
  passC_k<<<dim3(64, 32), 256, 0, stream>>>(Qb, Kb, Vtb, Scb, zcb, nw, Ob);
  gemm_out_k<<<dim3(8, 128), 256, 0, stream>>>(Ob, woB, (float*)d_out);
}

// Round 3
// 418.705 us; speedup vs baseline: 1.1682x; 1.1682x over previous
//
#include <hip/hip_runtime.h>
#include <stdint.h>

// B=4, S=4096, HID=1024, H=8, D=128, CHUNK=64, NC=64 chunks, BH=B*H=32
typedef __bf16 bf16x8 __attribute__((ext_vector_type(8)));
typedef float  f32x4  __attribute__((ext_vector_type(4)));

static __device__ __forceinline__ void gload16(const void* g, void* l) {
  __builtin_amdgcn_global_load_lds((__attribute__((address_space(1))) void*)g,
                                   (__attribute__((address_space(3))) void*)l,
                                   16, 0, 0);
}

static __device__ __forceinline__ f32x4 mfma16(bf16x8 a, bf16x8 b, f32x4 c) {
  return __builtin_amdgcn_mfma_f32_16x16x32_bf16(a, b, c, 0, 0, 0);
}

// ---------------- casts ----------------
__global__ __launch_bounds__(256) void cast8_k(const float* __restrict__ in,
                                               __bf16* __restrict__ out) {
  const size_t i = ((size_t)blockIdx.x * 256 + threadIdx.x) * 8;
  const float4 v0 = *(const float4*)(in + i);
  const float4 v1 = *(const float4*)(in + i + 4);
  bf16x8 o;
  o[0] = (__bf16)v0.x; o[1] = (__bf16)v0.y; o[2] = (__bf16)v0.z; o[3] = (__bf16)v0.w;
  o[4] = (__bf16)v1.x; o[5] = (__bf16)v1.y; o[6] = (__bf16)v1.z; o[7] = (__bf16)v1.w;
  *(bf16x8*)(out + i) = o;
}

__global__ __launch_bounds__(256) void castw_k(const float* __restrict__ w0, const float* __restrict__ w1,
                                               const float* __restrict__ w2, const float* __restrict__ w3,
                                               __bf16* __restrict__ o0, __bf16* __restrict__ o1,
                                               __bf16* __restrict__ o2, __bf16* __restrict__ o3) {
  const float* in; __bf16* out;
  switch (blockIdx.y) {
    case 0: in = w0; out = o0; break;
    case 1: in = w1; out = o1; break;
    case 2: in = w2; out = o2; break;
    default: in = w3; out = o3; break;
  }
  const size_t i = ((size_t)blockIdx.x * 256 + threadIdx.x) * 8;
  const float4 v0 = *(const float4*)(in + i);
  const float4 v1 = *(const float4*)(in + i + 4);
  bf16x8 o;
  o[0] = (__bf16)v0.x; o[1] = (__bf16)v0.y; o[2] = (__bf16)v0.z; o[3] = (__bf16)v0.w;
  o[4] = (__bf16)v1.x; o[5] = (__bf16)v1.y; o[6] = (__bf16)v1.z; o[7] = (__bf16)v1.w;
  *(bf16x8*)(out + i) = o;
}

// ---------------- QKV GEMM (C = A @ W^T), 128x128 tile, BK=32 ----------------
// z=0 -> Q rows; z=1 -> K rows + Kt[bh][d][s]; z=2 -> Vt[bh][e][s] (no V rows)
// Transposed outputs staged through LDS -> coalesced bf16x8 stores.
// XCD-aware bijective swizzle: 8 n-blocks sharing an A-tile land on one XCD.
__global__ __launch_bounds__(256)
void gemm_qkv_k(const __bf16* __restrict__ A,
                const __bf16* __restrict__ Bq, const __bf16* __restrict__ Bk, const __bf16* __restrict__ Bv,
                __bf16* __restrict__ Qo, __bf16* __restrict__ Ko,
                __bf16* __restrict__ Kt, __bf16* __restrict__ Vt) {
  alignas(16) __shared__ __bf16 sh[128 * 136];   // 34816 B; As/Bs live in K-loop, Ts after
  __bf16* As = sh;                 // 128*32
  __bf16* Bs = sh + 128 * 32;      // 128*32
  __bf16* Ts = sh;                 // 128 rows x pitch 136 (transposed tile)

  const int tid = threadIdx.x;
  // swizzle: flat in [0,3072), 3072 = 8 XCDs * 384
  const int flat = blockIdx.x + (blockIdx.y << 3) + (blockIdx.z << 10);
  const int sf = (flat & 7) * 384 + (flat >> 3);
  const int z = sf >> 10;
  const int rem = sf & 1023;
  const int m0 = (rem >> 3) * 128;
  const int n0 = (rem & 7) * 128;

  const __bf16* W = (z == 0) ? Bq : (z == 1) ? Bk : Bv;
  const int l = tid & 63, w = tid >> 6;
  const int wr = (w >> 1) * 64, wc = (w & 1) * 64;
  const int lr = l & 15, lk = (l >> 4) * 8;
  const int srow = tid >> 2, scol = (tid & 3) * 8;

  f32x4 acc[4][4] = {};
  for (int k0 = 0; k0 < 1024; k0 += 32) {
    gload16(A + (size_t)(m0 + srow) * 1024 + k0 + scol, &As[srow * 32 + scol]);
    gload16(A + (size_t)(m0 + 64 + srow) * 1024 + k0 + scol, &As[(64 + srow) * 32 + scol]);
    gload16(W + (size_t)(n0 + srow) * 1024 + k0 + scol, &Bs[srow * 32 + scol]);
    gload16(W + (size_t)(n0 + 64 + srow) * 1024 + k0 + scol, &Bs[(64 + srow) * 32 + scol]);
    __syncthreads();
    bf16x8 af[4], bfr[4];
#pragma unroll
    for (int mt = 0; mt < 4; ++mt) af[mt] = *(const bf16x8*)&As[(wr + mt * 16 + lr) * 32 + lk];
#pragma unroll
    for (int nt = 0; nt < 4; ++nt) bfr[nt] = *(const bf16x8*)&Bs[(wc + nt * 16 + lr) * 32 + lk];
#pragma unroll
    for (int mt = 0; mt < 4; ++mt)
#pragma unroll
      for (int nt = 0; nt < 4; ++nt)
        acc[mt][nt] = mfma16(af[mt], bfr[nt], acc[mt][nt]);
    __syncthreads();
  }

  // row stores (coalesced) for Q and K
  if (z <= 1) {
    __bf16* R = (z == 0) ? Qo : Ko;
#pragma unroll
    for (int mt = 0; mt < 4; ++mt)
#pragma unroll
      for (int r = 0; r < 4; ++r) {
        const int m = m0 + wr + mt * 16 + (l >> 4) * 4 + r;
#pragma unroll
        for (int nt = 0; nt < 4; ++nt)
          R[(size_t)m * 1024 + n0 + wc + nt * 16 + lr] = (__bf16)acc[mt][nt][r];
      }
  }
  // transposed stores (LDS-staged, coalesced) for Kt and Vt
  if (z >= 1) {
    // K-loop ended with __syncthreads -> As/Bs reads complete; safe to overwrite with Ts
#pragma unroll
    for (int mt = 0; mt < 4; ++mt)
#pragma unroll
      for (int r = 0; r < 4; ++r) {
        const int m = wr + mt * 16 + (l >> 4) * 4 + r;       // local row (s)
#pragma unroll
        for (int nt = 0; nt < 4; ++nt) {
          const int n = wc + nt * 16 + lr;                   // local col (d/e)
          Ts[n * 136 + m] = (__bf16)acc[mt][nt][r];
        }
      }
    __syncthreads();
    const int bb = m0 >> 12, s0 = m0 & 4095, hh = n0 >> 7;
    __bf16* T = (z == 1) ? Kt : Vt;
    const size_t tbase = ((size_t)((bb * 8 + hh) * 128)) * 4096 + s0;
#pragma unroll
    for (int it = 0; it < 8; ++it) {
      const int dd = it * 16 + (tid >> 4), s8 = (tid & 15) * 8;
      *(bf16x8*)(T + tbase + (size_t)dd * 4096 + s8) = *(const bf16x8*)&Ts[dd * 136 + s8];
    }
  }
}

// ---------------- output GEMM (f32 out), XCD-swizzled ----------------
__global__ __launch_bounds__(256)
void gemm_out_k(const __bf16* __restrict__ A, const __bf16* __restrict__ W,
                float* __restrict__ Co) {
  alignas(16) __shared__ __bf16 As[128 * 32];
  alignas(16) __shared__ __bf16 Bs[128 * 32];
  const int tid = threadIdx.x;
  const int flat = blockIdx.x + (blockIdx.y << 3);          // [0,1024)
  const int sf = (flat & 7) * 128 + (flat >> 3);
  const int m0 = (sf >> 3) * 128;
  const int n0 = (sf & 7) * 128;
  const int l = tid & 63, w = tid >> 6;
  const int wr = (w >> 1) * 64, wc = (w & 1) * 64;
  const int lr = l & 15, lk = (l >> 4) * 8;
  const int srow = tid >> 2, scol = (tid & 3) * 8;

  f32x4 acc[4][4] = {};
  for (int k0 = 0; k0 < 1024; k0 += 32) {
    gload16(A + (size_t)(m0 + srow) * 1024 + k0 + scol, &As[srow * 32 + scol]);
    gload16(A + (size_t)(m0 + 64 + srow) * 1024 + k0 + scol, &As[(64 + srow) * 32 + scol]);
    gload16(W + (size_t)(n0 + srow) * 1024 + k0 + scol, &Bs[srow * 32 + scol]);
    gload16(W + (size_t)(n0 + 64 + srow) * 1024 + k0 + scol, &Bs[(64 + srow) * 32 + scol]);
    __syncthreads();
    bf16x8 af[4], bfr[4];
#pragma unroll
    for (int mt = 0; mt < 4; ++mt) af[mt] = *(const bf16x8*)&As[(wr + mt * 16 + lr) * 32 + lk];
#pragma unroll
    for (int nt = 0; nt < 4; ++nt) bfr[nt] = *(const bf16x8*)&Bs[(wc + nt * 16 + lr) * 32 + lk];
#pragma unroll
    for (int mt = 0; mt < 4; ++mt)
#pragma unroll
      for (int nt = 0; nt < 4; ++nt)
        acc[mt][nt] = mfma16(af[mt], bfr[nt], acc[mt][nt]);
    __syncthreads();
  }
#pragma unroll
  for (int mt = 0; mt < 4; ++mt)
#pragma unroll
    for (int r = 0; r < 4; ++r) {
      const int m = m0 + wr + mt * 16 + (l >> 4) * 4 + r;
#pragma unroll
      for (int nt = 0; nt < 4; ++nt) {
        const int n = n0 + wc + nt * 16 + lr;
        Co[(size_t)m * 1024 + n] = acc[mt][nt][r];
      }
    }
}

// ---------------- z chunk sums: zc[bh][c][d] = sum_t K[c*64+t][d] ----------------
__global__ __launch_bounds__(128)
void z1_k(const __bf16* __restrict__ K, float* __restrict__ zc) {
  const int c = blockIdx.x, bh = blockIdx.y;
  const int bb = bh >> 3, hh = bh & 7;
  const int d = threadIdx.x;
  float a = 0.0f;
  for (int t = 0; t < 64; ++t)
    a += (float)K[((size_t)(bb * 4096 + c * 64 + t)) * 1024 + hh * 128 + d];
  zc[(size_t)(bh * 64 + c) * 128 + d] = a;
}

// in-place exclusive prefix of zc over chunks
__global__ __launch_bounds__(128)
void z2_k(float* __restrict__ zc) {
  const int bh = blockIdx.x;
  const int d = threadIdx.x;
  float run = 0.0f;
  for (int cc = 0; cc < 64; ++cc) {
    float* p = zc + (size_t)(bh * 64 + cc) * 128 + d;
    const float old = *p;
    *p = run;
    run += old;
  }
}

// ---------------- pass A: per-chunk S_T[e][d] = sum_t V[t,e]*K[t,d] ----------------
__global__ __launch_bounds__(256)
void passA_k(const __bf16* __restrict__ Kt, const __bf16* __restrict__ Vt,
             __bf16* __restrict__ Sc) {
  const int c = blockIdx.x, bh = blockIdx.y;
  const int tid = threadIdx.x, l = tid & 63, w = tid >> 6;
  const int wr = (w >> 1) * 64, wc = (w & 1) * 64;
  const int lr = l & 15, lk = (l >> 4) * 8;
  f32x4 acc[4][4] = {};
#pragma unroll
  for (int kk = 0; kk < 2; ++kk) {
    const int t = c * 64 + kk * 32 + lk;
    bf16x8 av[4], bk[4];
#pragma unroll
    for (int mt = 0; mt < 4; ++mt)
      av[mt] = *(const bf16x8*)(Vt + ((size_t)(bh * 128 + wr + mt * 16 + lr)) * 4096 + t);
#pragma unroll
    for (int nt = 0; nt < 4; ++nt)
      bk[nt] = *(const bf16x8*)(Kt + ((size_t)(bh * 128 + wc + nt * 16 + lr)) * 4096 + t);
#pragma unroll
    for (int mt = 0; mt < 4; ++mt)
#pragma unroll
      for (int nt = 0; nt < 4; ++nt)
        acc[mt][nt] = mfma16(av[mt], bk[nt], acc[mt][nt]);
  }
  const size_t sbase = ((size_t)(bh * 64 + c)) << 14;
#pragma unroll
  for (int mt = 0; mt < 4; ++mt)
#pragma unroll
    for (int r = 0; r < 4; ++r) {
      const int e = wr + mt * 16 + (l >> 4) * 4 + r;
#pragma unroll
      for (int nt = 0; nt < 4; ++nt) {
        const int d = wc + nt * 16 + lr;
        Sc[sbase + (size_t)e * 128 + d] = (__bf16)acc[mt][nt][r];
      }
    }
}

// ---------------- pass B: in-place exclusive prefix of Sc over chunks ----------------
__global__ __launch_bounds__(256)
void passB_k(__bf16* __restrict__ Sc) {
  const int bh = blockIdx.y;
  const int idx = blockIdx.x * 256 + threadIdx.x;
  float run = 0.0f;
  for (int cc = 0; cc < 64; ++cc) {
    __bf16* p = Sc + (((size_t)(bh * 64 + cc)) << 14) + idx;
    const float old = (float)*p;
    *p = (__bf16)run;
    run += old;
  }
}

// ---------------- pass C: outputs + denom + rmsnorm ----------------
__global__ __launch_bounds__(256)
void passC_k(const __bf16* __restrict__ Q, const __bf16* __restrict__ K,
             const __bf16* __restrict__ Vt, const __bf16* __restrict__ Sp,
             const float* __restrict__ zp, const float* __restrict__ nw,
             __bf16* __restrict__ O) {
  alignas(16) __shared__ __bf16 ScL[64 * 72];
  alignas(16) __shared__ float OL[64 * 132];
  alignas(16) __shared__ float zPL[128];
  alignas(16) __shared__ float nwL[128];
  alignas(16) __shared__ float dnL[64];
  const int c = blockIdx.x, bh = blockIdx.y;
  const int bb = bh >> 3, hh = bh & 7;
  const int tid = threadIdx.x, l = tid & 63, wv = tid >> 6;
  const int lr = l & 15, lk = (l >> 4) * 8;
  if (tid < 128) zPL[tid] = zp[(size_t)(bh * 64 + c) * 128 + tid];
  else nwL[tid - 128] = nw[tid - 128];

  const size_t qbase = ((size_t)(bb * 4096 + c * 64)) * 1024 + hh * 128;
  const size_t sbase = ((size_t)(bh * 64 + c)) << 14;

  f32x4 accO[4][2] = {};
  f32x4 accS[4] = {};
#pragma unroll
  for (int kk = 0; kk < 4; ++kk) {
    const int dof = kk * 32 + lk;
    bf16x8 aQ[4], bS[2], bK;
#pragma unroll
    for (int mt = 0; mt < 4; ++mt)
      aQ[mt] = *(const bf16x8*)(Q + qbase + (size_t)(mt * 16 + lr) * 1024 + dof);
#pragma unroll
    for (int nt = 0; nt < 2; ++nt)
      bS[nt] = *(const bf16x8*)(Sp + sbase + (size_t)(wv * 32 + nt * 16 + lr) * 128 + dof);
    bK = *(const bf16x8*)(K + qbase + (size_t)(wv * 16 + lr) * 1024 + dof);
#pragma unroll
    for (int mt = 0; mt < 4; ++mt) {
      accS[mt] = mfma16(aQ[mt], bK, accS[mt]);
#pragma unroll
      for (int nt = 0; nt < 2; ++nt)
        accO[mt][nt] = mfma16(aQ[mt], bS[nt], accO[mt][nt]);
    }
  }
  // masked scores -> LDS (bf16)
#pragma unroll
  for (int mt = 0; mt < 4; ++mt)
#pragma unroll
    for (int r = 0; r < 4; ++r) {
      const int srow = mt * 16 + (l >> 4) * 4 + r;
      const int tcol = wv * 16 + lr;
      ScL[srow * 72 + tcol] = (__bf16)((tcol <= srow) ? accS[mt][r] : 0.0f);
    }
  __syncthreads();
  // intra: acc += scores @ V   (B-operand = Vt rows)
#pragma unroll
  for (int kk2 = 0; kk2 < 2; ++kk2) {
    const int tof = kk2 * 32 + lk;
    bf16x8 aS[4], bV[2];
#pragma unroll
    for (int mt = 0; mt < 4; ++mt) aS[mt] = *(const bf16x8*)&ScL[(mt * 16 + lr) * 72 + tof];
#pragma unroll
    for (int nt = 0; nt < 2; ++nt)
      bV[nt] = *(const bf16x8*)(Vt + ((size_t)(bh * 128 + wv * 32 + nt * 16 + lr)) * 4096 + c * 64 + tof);
#pragma unroll
    for (int mt = 0; mt < 4; ++mt)
#pragma unroll
      for (int nt = 0; nt < 2; ++nt)
        accO[mt][nt] = mfma16(aS[mt], bV[nt], accO[mt][nt]);
  }
  // denom[s] = max(|q.z_prev + rowsum(masked scores)|, 1)
  if (tid < 64) {
    float rs = 0.0f;
    for (int t = 0; t < 64; ++t) rs += (float)ScL[tid * 72 + t];
    float qz = 0.0f;
    const __bf16* qrow = Q + qbase + (size_t)tid * 1024;
#pragma unroll
    for (int j = 0; j < 16; ++j) {
      const bf16x8 q8 = *(const bf16x8*)(qrow + j * 8);
#pragma unroll
      for (int i = 0; i < 8; ++i) qz += (float)q8[i] * zPL[j * 8 + i];
    }
    dnL[tid] = fmaxf(fabsf(qz + rs), 1.0f);
  }
  __syncthreads();
#pragma unroll
  for (int mt = 0; mt < 4; ++mt)
#pragma unroll
    for (int r = 0; r < 4; ++r) {
      const int row = mt * 16 + (l >> 4) * 4 + r;
#pragma unroll
      for (int nt = 0; nt < 2; ++nt) {
        const int col = wv * 32 + nt * 16 + lr;
        OL[row * 132 + col] = accO[mt][nt][r] / dnL[row];
      }
    }
  __syncthreads();
  // rmsnorm over D=128 + store bf16
  const int s = tid >> 2, e0 = (tid & 3) * 32;
  float ss = 0.0f;
  for (int i = 0; i < 32; ++i) { const float v = OL[s * 132 + e0 + i]; ss += v * v; }
  ss += __shfl_xor(ss, 1);
  ss += __shfl_xor(ss, 2);
  const float scale = rsqrtf(ss * (1.0f / 128.0f) + 1e-5f);
  __bf16* orow = O + qbase + (size_t)s * 1024 + e0;
#pragma unroll
  for (int i8 = 0; i8 < 4; ++i8) {
    bf16x8 ov;
#pragma unroll
    for (int j = 0; j < 8; ++j) {
      const int e = e0 + i8 * 8 + j;
      ov[j] = (__bf16)(OL[s * 132 + e] * scale * nwL[e]);
    }
    *(bf16x8*)(orow + i8 * 8) = ov;
  }
}

extern "C" void kernel_launch(void* const* d_in, const int* in_sizes, int n_in,
                              void* d_out, int out_size, void* d_ws, size_t ws_size,
                              hipStream_t stream) {
  (void)in_sizes; (void)n_in; (void)out_size; (void)ws_size;
  const float* hid = (const float*)d_in[0];
  const float* Wq  = (const float*)d_in[1];
  const float* Wk  = (const float*)d_in[2];
  const float* Wv  = (const float*)d_in[3];
  const float* Wo  = (const float*)d_in[4];
  const float* nw  = (const float*)d_in[5];

  char* ws = (char*)d_ws;
  size_t off = 0;
  auto nxt = [&](size_t bytes) -> char* {
    char* p = ws + off;
    off += (bytes + 255) & ~(size_t)255;
    return p;
  };
  __bf16* hA  = (__bf16*)nxt(33554432);   // hidden bf16 [16384][1024]; reused as Ob after gemm_qkv
  __bf16* wqB = (__bf16*)nxt(2097152);
  __bf16* wkB = (__bf16*)nxt(2097152);
  __bf16* wvB = (__bf16*)nxt(2097152);
  __bf16* woB = (__bf16*)nxt(2097152);
  __bf16* Qb  = (__bf16*)nxt(33554432);   // Q rows [16384][1024]
  __bf16* Kb  = (__bf16*)nxt(33554432);   // K rows
  __bf16* Ktb = (__bf16*)nxt(33554432);   // K^T [bh][d][s]
  __bf16* Vtb = (__bf16*)nxt(33554432);   // V^T [bh][e][s]
  __bf16* Scb = (__bf16*)nxt(67108864);   // chunk states -> exclusive prefix [bh][c][e][d]
  float*  zcb = (float*)nxt(1048576);     // chunk z sums -> exclusive prefix [bh][c][d]
  __bf16* Ob  = hA;                       // alias: hA dead after gemm_qkv_k (ws stays < 256 MiB)

  cast8_k<<<8192, 256, 0, stream>>>(hid, hA);
  castw_k<<<dim3(512, 4), 256, 0, stream>>>(Wq, Wk, Wv, Wo, wqB, wkB, wvB, woB);
  gemm_qkv_k<<<dim3(8, 128, 3), 256, 0, stream>>>(hA, wqB, wkB, wvB, Qb, Kb, Ktb, Vtb);
  z1_k<<<dim3(64, 32), 128, 0, stream>>>(Kb, zcb);
  passA_k<<<dim3(64, 32), 256, 0, stream>>>(Ktb, Vtb, Scb);
  passB_k<<<dim3(64, 32), 256, 0, stream>>>(Scb);
  z2_k<<<32, 128, 0, stream>>>(zcb);
  passC_k<<<dim3(64, 32), 256, 0, stream>>>(Qb, Kb, Vtb, Scb, zcb, nw, Ob);
  gemm_out_k<<<dim3(8, 128), 256, 0, stream>>>(Ob, woB, (float*)d_out);
}

// Round 6
// 385.685 us; speedup vs baseline: 1.2682x; 1.0856x over previous
//
#include <hip/hip_runtime.h>
#include <stdint.h>

// B=4, S=4096, HID=1024, H=8, D=128, CHUNK=64, NC=64 chunks, BH=B*H=32
typedef __bf16 bf16x8 __attribute__((ext_vector_type(8)));
typedef float  f32x4  __attribute__((ext_vector_type(4)));

static __device__ __forceinline__ void gload16(const void* g, void* l) {
  __builtin_amdgcn_global_load_lds((__attribute__((address_space(1))) void*)g,
                                   (__attribute__((address_space(3))) void*)l,
                                   16, 0, 0);
}

static __device__ __forceinline__ f32x4 mfma16(bf16x8 a, bf16x8 b, f32x4 c) {
  return __builtin_amdgcn_mfma_f32_16x16x32_bf16(a, b, c, 0, 0, 0);
}

#define MEMFENCE asm volatile("" ::: "memory")

// ---------------- casts ----------------
__global__ __launch_bounds__(256) void cast8_k(const float* __restrict__ in,
                                               __bf16* __restrict__ out) {
  const size_t i = ((size_t)blockIdx.x * 256 + threadIdx.x) * 8;
  const float4 v0 = *(const float4*)(in + i);
  const float4 v1 = *(const float4*)(in + i + 4);
  bf16x8 o;
  o[0] = (__bf16)v0.x; o[1] = (__bf16)v0.y; o[2] = (__bf16)v0.z; o[3] = (__bf16)v0.w;
  o[4] = (__bf16)v1.x; o[5] = (__bf16)v1.y; o[6] = (__bf16)v1.z; o[7] = (__bf16)v1.w;
  *(bf16x8*)(out + i) = o;
}

__global__ __launch_bounds__(256) void castw_k(const float* __restrict__ w0, const float* __restrict__ w1,
                                               const float* __restrict__ w2, const float* __restrict__ w3,
                                               __bf16* __restrict__ o0, __bf16* __restrict__ o1,
                                               __bf16* __restrict__ o2, __bf16* __restrict__ o3) {
  const float* in; __bf16* out;
  switch (blockIdx.y) {
    case 0: in = w0; out = o0; break;
    case 1: in = w1; out = o1; break;
    case 2: in = w2; out = o2; break;
    default: in = w3; out = o3; break;
  }
  const size_t i = ((size_t)blockIdx.x * 256 + threadIdx.x) * 8;
  const float4 v0 = *(const float4*)(in + i);
  const float4 v1 = *(const float4*)(in + i + 4);
  bf16x8 o;
  o[0] = (__bf16)v0.x; o[1] = (__bf16)v0.y; o[2] = (__bf16)v0.z; o[3] = (__bf16)v0.w;
  o[4] = (__bf16)v1.x; o[5] = (__bf16)v1.y; o[6] = (__bf16)v1.z; o[7] = (__bf16)v1.w;
  *(bf16x8*)(out + i) = o;
}

// ============ 256x256 tile, BK=64, 8 waves (2Mx4N), 128 KiB LDS, 8-phase ============
// LDS map (bf16 elems), per buf (stride 32768):
//   A-L @ 0     : A rows {0-63,128-191}   (rel m0), read ONLY in ph0
//   A-H @ 8192  : A rows {64-127,192-255},read ONLY in ph2
//   B-L @ 16384 : W rows {0-31,64-95,128-159,192-223} (rel n0), read ph0+ph3
//   B-H @ 24576 : W rows {32-63,96-127,160-191,224-255},        read ph1
// Swizzle (both sides): LDS[r][sl] holds global k-slot (sl ^ (r&7)); r&7 == lo&7 on reads.
// Staging per tile t: ph0->B-L(t+1) [other buf]; ph1->A-L(t+2); ph2->B-H(t+2); ph3->A-H(t+2)
//   [cur buf, each strictly after its region's last read-barrier].
// Boundary wait: vmcnt(6) for t<14 (3 staged regions in flight), vmcnt(0) at tail.
static __device__ __forceinline__ void kloop256(
    const __bf16* __restrict__ A, const __bf16* __restrict__ W,
    int m0, int n0, __bf16* sh, int tid, f32x4 acc[8][4]) {
  const int l = tid & 63;
  const int wv = tid >> 6;
  const int wm = wv >> 2, wn = wv & 3;
  const int lo = l & 15, kq = l >> 4;

  auto SA = [&](int kt, int h) {   // h=0 -> A-L, h=1 -> A-H
#pragma unroll
    for (int j = 0; j < 2; ++j) {
      const int p = j * 512 + tid;
      const int r = p >> 3, sl = p & 7;
      const int grow = m0 + h * 64 + (r & 63) + (r >> 6) * 128;
      gload16(A + (size_t)grow * 1024 + (kt << 6) + ((sl ^ (r & 7)) << 3),
              sh + (kt & 1) * 32768 + h * 8192 + p * 8);
    }
  };
  auto SB = [&](int kt, int h) {   // h=0 -> B-L, h=1 -> B-H
#pragma unroll
    for (int j = 0; j < 2; ++j) {
      const int p = j * 512 + tid;
      const int r = p >> 3, sl = p & 7;
      const int grow = n0 + h * 32 + (r & 31) + (r >> 5) * 64;
      gload16(W + (size_t)grow * 1024 + (kt << 6) + ((sl ^ (r & 7)) << 3),
              sh + (kt & 1) * 32768 + 16384 + h * 8192 + p * 8);
    }
  };
  auto LDA = [&](int cur, int mh, int mi, int ks) -> bf16x8 {
    const int r = wm * 64 + mi * 16 + lo;
    return *(const bf16x8*)&sh[cur * 32768 + mh * 8192 + r * 64 + (((ks * 4 + kq) ^ (r & 7)) << 3)];
  };
  auto LDB = [&](int cur, int nh, int ni, int ks) -> bf16x8 {
    const int r = wn * 32 + ni * 16 + lo;
    return *(const bf16x8*)&sh[cur * 32768 + 16384 + nh * 8192 + r * 64 + (((ks * 4 + kq) ^ (r & 7)) << 3)];
  };

  // prologue: tile0 fully + tile1 {A-L,B-H,A-H}; B-L(1) comes from tile0 ph0.
  SA(0, 0); SB(0, 0); SB(0, 1); SA(0, 1);
  SA(1, 0); SB(1, 1); SA(1, 1);
  MEMFENCE;
  asm volatile("s_waitcnt vmcnt(6)" ::: "memory");
  __builtin_amdgcn_s_barrier();

  bf16x8 a[4][2], b[2][2], b2[2][2];
#pragma unroll 2
  for (int t = 0; t < 16; ++t) {
    const int cur = t & 1;
    // ---------- phase 0: C(m 0..3, n 0..1) ; reads A-L, B-L ----------
#pragma unroll
    for (int mi = 0; mi < 4; ++mi)
#pragma unroll
      for (int ks = 0; ks < 2; ++ks) a[mi][ks] = LDA(cur, 0, mi, ks);
#pragma unroll
    for (int ni = 0; ni < 2; ++ni)
#pragma unroll
      for (int ks = 0; ks < 2; ++ks) b[ni][ks] = LDB(cur, 0, ni, ks);
    if (t + 1 < 16) SB(t + 1, 0);
    MEMFENCE;
    __builtin_amdgcn_s_barrier();
    asm volatile("s_waitcnt lgkmcnt(0)" ::: "memory");
    __builtin_amdgcn_sched_barrier(0);
    __builtin_amdgcn_s_setprio(1);
#pragma unroll
    for (int mi = 0; mi < 4; ++mi)
#pragma unroll
      for (int ni = 0; ni < 2; ++ni)
#pragma unroll
        for (int ks = 0; ks < 2; ++ks)
          acc[mi][ni] = mfma16(a[mi][ks], b[ni][ks], acc[mi][ni]);
    __builtin_amdgcn_s_setprio(0);
    MEMFENCE;
    __builtin_amdgcn_s_barrier();
    // ---------- phase 1: C(m 0..3, n 2..3) ; reads B-H ----------
#pragma unroll
    for (int ni = 0; ni < 2; ++ni)
#pragma unroll
      for (int ks = 0; ks < 2; ++ks) b2[ni][ks] = LDB(cur, 1, ni, ks);
    if (t + 2 < 16) SA(t + 2, 0);   // clobbers A-L(cur): fully read in ph0
    MEMFENCE;
    __builtin_amdgcn_s_barrier();
    asm volatile("s_waitcnt lgkmcnt(0)" ::: "memory");
    __builtin_amdgcn_sched_barrier(0);
    __builtin_amdgcn_s_setprio(1);
#pragma unroll
    for (int mi = 0; mi < 4; ++mi)
#pragma unroll
      for (int ni = 0; ni < 2; ++ni)
#pragma unroll
        for (int ks = 0; ks < 2; ++ks)
          acc[mi][2 + ni] = mfma16(a[mi][ks], b2[ni][ks], acc[mi][2 + ni]);
    __builtin_amdgcn_s_setprio(0);
    MEMFENCE;
    __builtin_amdgcn_s_barrier();
    // ---------- phase 2: C(m 4..7, n 2..3) ; reads A-H (b2 in regs) ----------
#pragma unroll
    for (int mi = 0; mi < 4; ++mi)
#pragma unroll
      for (int ks = 0; ks < 2; ++ks) a[mi][ks] = LDA(cur, 1, mi, ks);
    if (t + 2 < 16) SB(t + 2, 1);   // clobbers B-H(cur): fully read in ph1
    MEMFENCE;
    __builtin_amdgcn_s_barrier();
    asm volatile("s_waitcnt lgkmcnt(0)" ::: "memory");
    __builtin_amdgcn_sched_barrier(0);
    __builtin_amdgcn_s_setprio(1);
#pragma unroll
    for (int mi = 0; mi < 4; ++mi)
#pragma unroll
      for (int ni = 0; ni < 2; ++ni)
#pragma unroll
        for (int ks = 0; ks < 2; ++ks)
          acc[4 + mi][2 + ni] = mfma16(a[mi][ks], b2[ni][ks], acc[4 + mi][2 + ni]);
    __builtin_amdgcn_s_setprio(0);
    MEMFENCE;
    __builtin_amdgcn_s_barrier();
    // ---------- phase 3: C(m 4..7, n 0..1) ; reads B-L again (a in regs) ----------
#pragma unroll
    for (int ni = 0; ni < 2; ++ni)
#pragma unroll
      for (int ks = 0; ks < 2; ++ks) b[ni][ks] = LDB(cur, 0, ni, ks);
    if (t + 2 < 16) SA(t + 2, 1);   // clobbers A-H(cur): fully read in ph2
    MEMFENCE;
    __builtin_amdgcn_s_barrier();
    asm volatile("s_waitcnt lgkmcnt(0)" ::: "memory");
    __builtin_amdgcn_sched_barrier(0);
    __builtin_amdgcn_s_setprio(1);
#pragma unroll
    for (int mi = 0; mi < 4; ++mi)
#pragma unroll
      for (int ni = 0; ni < 2; ++ni)
#pragma unroll
        for (int ks = 0; ks < 2; ++ks)
          acc[4 + mi][ni] = mfma16(a[mi][ks], b[ni][ks], acc[4 + mi][ni]);
    __builtin_amdgcn_s_setprio(0);
    if (t < 14) asm volatile("s_waitcnt vmcnt(6)" ::: "memory");
    else        asm volatile("s_waitcnt vmcnt(0)" ::: "memory");
    MEMFENCE;
    __builtin_amdgcn_s_barrier();
  }
}

// QKV: grid 768 = 3z x 64m x 4n, XCD-swizzled. z=0 Q rows; z=1 K rows + Kt; z=2 Vt.
__global__ __launch_bounds__(512, 2)
void gemm_qkv8_k(const __bf16* __restrict__ A,
                 const __bf16* __restrict__ Bq, const __bf16* __restrict__ Bk, const __bf16* __restrict__ Bv,
                 __bf16* __restrict__ Qo, __bf16* __restrict__ Ko,
                 __bf16* __restrict__ Kt, __bf16* __restrict__ Vt) {
  extern __shared__ __bf16 sh[];
  const int tid = threadIdx.x;
  const int flat = blockIdx.x;                     // [0,768), 768 = 8*96
  const int sf = (flat & 7) * 96 + (flat >> 3);
  const int z = sf >> 8;
  const int rem = sf & 255;
  const int m0 = (rem >> 2) * 256;
  const int n0 = (rem & 3) * 256;
  const __bf16* W = (z == 0) ? Bq : (z == 1) ? Bk : Bv;

  f32x4 acc[8][4] = {};
  kloop256(A, W, m0, n0, sh, tid, acc);

  const int l = tid & 63, wv = tid >> 6, wm = wv >> 2, wn = wv & 3;
  const int lo = l & 15, kq = l >> 4;

  // ---- row stores (Q / K) via LDS bounce: 2 passes over n-halves, [m][n] pitch 136 ----
  if (z <= 1) {
    __bf16* R = z ? Ko : Qo;
#pragma unroll
    for (int nh = 0; nh < 2; ++nh) {
      if ((wn >> 1) == nh) {
#pragma unroll
        for (int mi = 0; mi < 8; ++mi)
#pragma unroll
          for (int ni = 0; ni < 4; ++ni)
#pragma unroll
            for (int rr = 0; rr < 4; ++rr)
              sh[wm * 17408 + (mi * 16 + kq * 4 + rr) * 136 + (wn & 1) * 64 + ni * 16 + lo]
                  = (__bf16)acc[mi][ni][rr];
      }
      __syncthreads();
#pragma unroll
      for (int it = 0; it < 8; ++it) {
        const int idx = it * 512 + tid;
        const int rg = idx >> 11, mrow = (idx >> 4) & 127, sl = idx & 15;
        *(bf16x8*)(R + (size_t)(m0 + rg * 128 + mrow) * 1024 + n0 + nh * 128 + sl * 8)
            = *(const bf16x8*)&sh[rg * 17408 + mrow * 136 + sl * 8];
      }
      __syncthreads();
    }
  }
  // ---- transposed stores (Kt / Vt): 2 passes, [n][m] pitch 136 ----
  if (z >= 1) {
    __bf16* T = (z == 1) ? Kt : Vt;
    const int bb = m0 >> 12, s0v = m0 & 4095, h0 = n0 >> 7;
#pragma unroll
    for (int nh = 0; nh < 2; ++nh) {
      if ((wn >> 1) == nh) {
#pragma unroll
        for (int mi = 0; mi < 8; ++mi)
#pragma unroll
          for (int ni = 0; ni < 4; ++ni)
#pragma unroll
            for (int rr = 0; rr < 4; ++rr)
              sh[wm * 17408 + ((wn & 1) * 64 + ni * 16 + lo) * 136 + mi * 16 + kq * 4 + rr]
                  = (__bf16)acc[mi][ni][rr];
      }
      __syncthreads();
      const int hh = h0 + nh;
#pragma unroll
      for (int it = 0; it < 8; ++it) {
        const int idx = it * 512 + tid;
        const int rg = idx >> 11, dr = (idx >> 4) & 127, sl = idx & 15;
        *(bf16x8*)(T + ((size_t)((bb * 8 + hh) * 128 + dr)) * 4096 + s0v + rg * 128 + sl * 8)
            = *(const bf16x8*)&sh[rg * 17408 + dr * 136 + sl * 8];
      }
      __syncthreads();
    }
  }
}

// output GEMM (f32 out): grid 256 = 64m x 4n, XCD-swizzled
__global__ __launch_bounds__(512, 2)
void gemm_out8_k(const __bf16* __restrict__ A, const __bf16* __restrict__ W,
                 float* __restrict__ Co) {
  extern __shared__ __bf16 sh[];
  const int tid = threadIdx.x;
  const int flat = blockIdx.x;                     // [0,256)
  const int sf = (flat & 7) * 32 + (flat >> 3);
  const int m0 = (sf >> 2) * 256;
  const int n0 = (sf & 3) * 256;

  f32x4 acc[8][4] = {};
  kloop256(A, W, m0, n0, sh, tid, acc);

  const int l = tid & 63, wv = tid >> 6, wm = wv >> 2, wn = wv & 3;
  const int lo = l & 15, kq = l >> 4;
#pragma unroll
  for (int mi = 0; mi < 8; ++mi)
#pragma unroll
    for (int ni = 0; ni < 4; ++ni)
#pragma unroll
      for (int rr = 0; rr < 4; ++rr)
        Co[(size_t)(m0 + wm * 128 + mi * 16 + kq * 4 + rr) * 1024 + n0 + wn * 64 + ni * 16 + lo]
            = acc[mi][ni][rr];
}

// ---------------- z chunk sums: zc[bh][c][d] = sum_t K[c*64+t][d] ----------------
__global__ __launch_bounds__(128)
void z1_k(const __bf16* __restrict__ K, float* __restrict__ zc) {
  const int c = blockIdx.x, bh = blockIdx.y;
  const int bb = bh >> 3, hh = bh & 7;
  const int d = threadIdx.x;
  float a = 0.0f;
  for (int t = 0; t < 64; ++t)
    a += (float)K[((size_t)(bb * 4096 + c * 64 + t)) * 1024 + hh * 128 + d];
  zc[(size_t)(bh * 64 + c) * 128 + d] = a;
}

// in-place exclusive prefix of zc over chunks
__global__ __launch_bounds__(128)
void z2_k(float* __restrict__ zc) {
  const int bh = blockIdx.x;
  const int d = threadIdx.x;
  float run = 0.0f;
  for (int cc = 0; cc < 64; ++cc) {
    float* p = zc + (size_t)(bh * 64 + cc) * 128 + d;
    const float old = *p;
    *p = run;
    run += old;
  }
}

// ---------------- pass A: per-chunk S_T[e][d] = sum_t V[t,e]*K[t,d] ----------------
__global__ __launch_bounds__(256)
void passA_k(const __bf16* __restrict__ Kt, const __bf16* __restrict__ Vt,
             __bf16* __restrict__ Sc) {
  const int c = blockIdx.x, bh = blockIdx.y;
  const int tid = threadIdx.x, l = tid & 63, w = tid >> 6;
  const int wr = (w >> 1) * 64, wc = (w & 1) * 64;
  const int lr = l & 15, lk = (l >> 4) * 8;
  f32x4 acc[4][4] = {};
#pragma unroll
  for (int kk = 0; kk < 2; ++kk) {
    const int t = c * 64 + kk * 32 + lk;
    bf16x8 av[4], bk[4];
#pragma unroll
    for (int mt = 0; mt < 4; ++mt)
      av[mt] = *(const bf16x8*)(Vt + ((size_t)(bh * 128 + wr + mt * 16 + lr)) * 4096 + t);
#pragma unroll
    for (int nt = 0; nt < 4; ++nt)
      bk[nt] = *(const bf16x8*)(Kt + ((size_t)(bh * 128 + wc + nt * 16 + lr)) * 4096 + t);
#pragma unroll
    for (int mt = 0; mt < 4; ++mt)
#pragma unroll
      for (int nt = 0; nt < 4; ++nt)
        acc[mt][nt] = mfma16(av[mt], bk[nt], acc[mt][nt]);
  }
  const size_t sbase = ((size_t)(bh * 64 + c)) << 14;
#pragma unroll
  for (int mt = 0; mt < 4; ++mt)
#pragma unroll
    for (int r = 0; r < 4; ++r) {
      const int e = wr + mt * 16 + (l >> 4) * 4 + r;
#pragma unroll
      for (int nt = 0; nt < 4; ++nt) {
        const int d = wc + nt * 16 + lr;
        Sc[sbase + (size_t)e * 128 + d] = (__bf16)acc[mt][nt][r];
      }
    }
}

// ---------------- pass B: in-place exclusive prefix of Sc over chunks ----------------
__global__ __launch_bounds__(256)
void passB_k(__bf16* __restrict__ Sc) {
  const int bh = blockIdx.y;
  const int idx = blockIdx.x * 256 + threadIdx.x;
  float run = 0.0f;
  for (int cc = 0; cc < 64; ++cc) {
    __bf16* p = Sc + (((size_t)(bh * 64 + cc)) << 14) + idx;
    const float old = (float)*p;
    *p = (__bf16)run;
    run += old;
  }
}

// ---------------- pass C: outputs + denom + rmsnorm ----------------
__global__ __launch_bounds__(256)
void passC_k(const __bf16* __restrict__ Q, const __bf16* __restrict__ K,
             const __bf16* __restrict__ Vt, const __bf16* __restrict__ Sp,
             const float* __restrict__ zp, const float* __restrict__ nw,
             __bf16* __restrict__ O) {
  alignas(16) __shared__ __bf16 ScL[64 * 72];
  alignas(16) __shared__ float OL[64 * 132];
  alignas(16) __shared__ float zPL[128];
  alignas(16) __shared__ float nwL[128];
  alignas(16) __shared__ float dnL[64];
  const int c = blockIdx.x, bh = blockIdx.y;
  const int bb = bh >> 3, hh = bh & 7;
  const int tid = threadIdx.x, l = tid & 63, wv = tid >> 6;
  const int lr = l & 15, lk = (l >> 4) * 8;
  if (tid < 128) zPL[tid] = zp[(size_t)(bh * 64 + c) * 128 + tid];
  else nwL[tid - 128] = nw[tid - 128];

  const size_t qbase = ((size_t)(bb * 4096 + c * 64)) * 1024 + hh * 128;
  const size_t sbase = ((size_t)(bh * 64 + c)) << 14;

  f32x4 accO[4][2] = {};
  f32x4 accS[4] = {};
#pragma unroll
  for (int kk = 0; kk < 4; ++kk) {
    const int dof = kk * 32 + lk;
    bf16x8 aQ[4], bS[2], bK;
#pragma unroll
    for (int mt = 0; mt < 4; ++mt)
      aQ[mt] = *(const bf16x8*)(Q + qbase + (size_t)(mt * 16 + lr) * 1024 + dof);
#pragma unroll
    for (int nt = 0; nt < 2; ++nt)
      bS[nt] = *(const bf16x8*)(Sp + sbase + (size_t)(wv * 32 + nt * 16 + lr) * 128 + dof);
    bK = *(const bf16x8*)(K + qbase + (size_t)(wv * 16 + lr) * 1024 + dof);
#pragma unroll
    for (int mt = 0; mt < 4; ++mt) {
      accS[mt] = mfma16(aQ[mt], bK, accS[mt]);
#pragma unroll
      for (int nt = 0; nt < 2; ++nt)
        accO[mt][nt] = mfma16(aQ[mt], bS[nt], accO[mt][nt]);
    }
  }
  // masked scores -> LDS (bf16)
#pragma unroll
  for (int mt = 0; mt < 4; ++mt)
#pragma unroll
    for (int r = 0; r < 4; ++r) {
      const int srow = mt * 16 + (l >> 4) * 4 + r;
      const int tcol = wv * 16 + lr;
      ScL[srow * 72 + tcol] = (__bf16)((tcol <= srow) ? accS[mt][r] : 0.0f);
    }
  __syncthreads();
  // intra: acc += scores @ V   (B-operand = Vt rows)
#pragma unroll
  for (int kk2 = 0; kk2 < 2; ++kk2) {
    const int tof = kk2 * 32 + lk;
    bf16x8 aS[4], bV[2];
#pragma unroll
    for (int mt = 0; mt < 4; ++mt) aS[mt] = *(const bf16x8*)&ScL[(mt * 16 + lr) * 72 + tof];
#pragma unroll
    for (int nt = 0; nt < 2; ++nt)
      bV[nt] = *(const bf16x8*)(Vt + ((size_t)(bh * 128 + wv * 32 + nt * 16 + lr)) * 4096 + c * 64 + tof);
#pragma unroll
    for (int mt = 0; mt < 4; ++mt)
#pragma unroll
      for (int nt = 0; nt < 2; ++nt)
        accO[mt][nt] = mfma16(aS[mt], bV[nt], accO[mt][nt]);
  }
  // denom[s] = max(|q.z_prev + rowsum(masked scores)|, 1)
  if (tid < 64) {
    float rs = 0.0f;
    for (int t = 0; t < 64; ++t) rs += (float)ScL[tid * 72 + t];
    float qz = 0.0f;
    const __bf16* qrow = Q + qbase + (size_t)tid * 1024;
#pragma unroll
    for (int j = 0; j < 16; ++j) {
      const bf16x8 q8 = *(const bf16x8*)(qrow + j * 8);
#pragma unroll
      for (int i = 0; i < 8; ++i) qz += (float)q8[i] * zPL[j * 8 + i];
    }
    dnL[tid] = fmaxf(fabsf(qz + rs), 1.0f);
  }
  __syncthreads();
#pragma unroll
  for (int mt = 0; mt < 4; ++mt)
#pragma unroll
    for (int r = 0; r < 4; ++r) {
      const int row = mt * 16 + (l >> 4) * 4 + r;
#pragma unroll
      for (int nt = 0; nt < 2; ++nt) {
        const int col = wv * 32 + nt * 16 + lr;
        OL[row * 132 + col] = accO[mt][nt][r] / dnL[row];
      }
    }
  __syncthreads();
  // rmsnorm over D=128 + store bf16
  const int s = tid >> 2, e0 = (tid & 3) * 32;
  float ss = 0.0f;
  for (int i = 0; i < 32; ++i) { const float v = OL[s * 132 + e0 + i]; ss += v * v; }
  ss += __shfl_xor(ss, 1);
  ss += __shfl_xor(ss, 2);
  const float scale = rsqrtf(ss * (1.0f / 128.0f) + 1e-5f);
  __bf16* orow = O + qbase + (size_t)s * 1024 + e0;
#pragma unroll
  for (int i8 = 0; i8 < 4; ++i8) {
    bf16x8 ov;
#pragma unroll
    for (int j = 0; j < 8; ++j) {
      const int e = e0 + i8 * 8 + j;
      ov[j] = (__bf16)(OL[s * 132 + e] * scale * nwL[e]);
    }
    *(bf16x8*)(orow + i8 * 8) = ov;
  }
}

extern "C" void kernel_launch(void* const* d_in, const int* in_sizes, int n_in,
                              void* d_out, int out_size, void* d_ws, size_t ws_size,
                              hipStream_t stream) {
  (void)in_sizes; (void)n_in; (void)out_size; (void)ws_size;
  const float* hid = (const float*)d_in[0];
  const float* Wq  = (const float*)d_in[1];
  const float* Wk  = (const float*)d_in[2];
  const float* Wv  = (const float*)d_in[3];
  const float* Wo  = (const float*)d_in[4];
  const float* nw  = (const float*)d_in[5];

  char* ws = (char*)d_ws;
  size_t off = 0;
  auto nxt = [&](size_t bytes) -> char* {
    char* p = ws + off;
    off += (bytes + 255) & ~(size_t)255;
    return p;
  };
  __bf16* hA  = (__bf16*)nxt(33554432);   // hidden bf16 [16384][1024]; reused as Ob after gemm_qkv
  __bf16* wqB = (__bf16*)nxt(2097152);
  __bf16* wkB = (__bf16*)nxt(2097152);
  __bf16* wvB = (__bf16*)nxt(2097152);
  __bf16* woB = (__bf16*)nxt(2097152);
  __bf16* Qb  = (__bf16*)nxt(33554432);   // Q rows [16384][1024]
  __bf16* Kb  = (__bf16*)nxt(33554432);   // K rows
  __bf16* Ktb = (__bf16*)nxt(33554432);   // K^T [bh][d][s]
  __bf16* Vtb = (__bf16*)nxt(33554432);   // V^T [bh][e][s]
  __bf16* Scb = (__bf16*)nxt(67108864);   // chunk states -> exclusive prefix [bh][c][e][d]
  float*  zcb = (float*)nxt(1048576);     // chunk z sums -> exclusive prefix [bh][c][d]
  __bf16* Ob  = hA;                       // alias: hA dead after gemm_qkv8_k

  cast8_k<<<8192, 256, 0, stream>>>(hid, hA);
  castw_k<<<dim3(512, 4), 256, 0, stream>>>(Wq, Wk, Wv, Wo, wqB, wkB, wvB, woB);
  gemm_qkv8_k<<<768, 512, 131072, stream>>>(hA, wqB, wkB, wvB, Qb, Kb, Ktb, Vtb);
  z1_k<<<dim3(64, 32), 128, 0, stream>>>(Kb, zcb);
  passA_k<<<dim3(64, 32), 256, 0, stream>>>(Ktb, Vtb, Scb);
  passB_k<<<dim3(64, 32), 256, 0, stream>>>(Scb);
  z2_k<<<32, 128, 0, stream>>>(zcb);
  passC_k<<<dim3(64, 32), 256, 0, stream>>>(Qb, Kb, Vtb, Scb, zcb, nw, Ob);
  gemm_out8_k<<<256, 512, 131072, stream>>>(Ob, woB, (float*)d_out);
}

// Round 8
// 368.094 us; speedup vs baseline: 1.3288x; 1.0478x over previous
//
#include <hip/hip_runtime.h>
#include <stdint.h>

// B=4, S=4096, HID=1024, H=8, D=128, CHUNK=64, NC=64 chunks, BH=B*H=32
typedef __bf16 bf16x8 __attribute__((ext_vector_type(8)));
typedef float  f32x4  __attribute__((ext_vector_type(4)));

static __device__ __forceinline__ void gload16(const void* g, void* l) {
  __builtin_amdgcn_global_load_lds((__attribute__((address_space(1))) void*)g,
                                   (__attribute__((address_space(3))) void*)l,
                                   16, 0, 0);
}

static __device__ __forceinline__ f32x4 mfma16(bf16x8 a, bf16x8 b, f32x4 c) {
  return __builtin_amdgcn_mfma_f32_16x16x32_bf16(a, b, c, 0, 0, 0);
}

#define MEMFENCE asm volatile("" ::: "memory")

// ---------------- casts ----------------
__global__ __launch_bounds__(256) void cast8_k(const float* __restrict__ in,
                                               __bf16* __restrict__ out) {
  const size_t i = ((size_t)blockIdx.x * 256 + threadIdx.x) * 8;
  const float4 v0 = *(const float4*)(in + i);
  const float4 v1 = *(const float4*)(in + i + 4);
  bf16x8 o;
  o[0] = (__bf16)v0.x; o[1] = (__bf16)v0.y; o[2] = (__bf16)v0.z; o[3] = (__bf16)v0.w;
  o[4] = (__bf16)v1.x; o[5] = (__bf16)v1.y; o[6] = (__bf16)v1.z; o[7] = (__bf16)v1.w;
  *(bf16x8*)(out + i) = o;
}

__global__ __launch_bounds__(256) void castw_k(const float* __restrict__ w0, const float* __restrict__ w1,
                                               const float* __restrict__ w2, const float* __restrict__ w3,
                                               __bf16* __restrict__ o0, __bf16* __restrict__ o1,
                                               __bf16* __restrict__ o2, __bf16* __restrict__ o3) {
  const float* in; __bf16* out;
  switch (blockIdx.y) {
    case 0: in = w0; out = o0; break;
    case 1: in = w1; out = o1; break;
    case 2: in = w2; out = o2; break;
    default: in = w3; out = o3; break;
  }
  const size_t i = ((size_t)blockIdx.x * 256 + threadIdx.x) * 8;
  const float4 v0 = *(const float4*)(in + i);
  const float4 v1 = *(const float4*)(in + i + 4);
  bf16x8 o;
  o[0] = (__bf16)v0.x; o[1] = (__bf16)v0.y; o[2] = (__bf16)v0.z; o[3] = (__bf16)v0.w;
  o[4] = (__bf16)v1.x; o[5] = (__bf16)v1.y; o[6] = (__bf16)v1.z; o[7] = (__bf16)v1.w;
  *(bf16x8*)(out + i) = o;
}

// ============ 256x256 tile, BK=64, 8 waves (2Mx4N), 128 KiB LDS, 4-phase/tile ============
// LDS map per buf (stride 32768): A-L@0 (ph0), A-H@8192 (ph2), B-L@16384 (ph0+ph3), B-H@24576 (ph1)
// Swizzle both sides: LDS[r][sl] holds global k-slot (sl ^ (r&7)).
// Staging per tile t: ph0->B-L(t+1) [other buf]; ph1->A-L(t+2); ph2->B-H(t+2); ph3->A-H(t+2)
//   (each stage targets a region whose last ds_read completed in a PREVIOUS phase, behind
//    that phase's end-barrier -> the pre-MFMA barrier is redundant and removed: 4 barriers/tile).
// Boundary wait: vmcnt(6) for t<14, vmcnt(0) at tail.
static __device__ __forceinline__ void kloop256(
    const __bf16* __restrict__ A, const __bf16* __restrict__ W,
    int m0, int n0, __bf16* sh, int tid, f32x4 acc[8][4]) {
  const int l = tid & 63;
  const int wv = tid >> 6;
  const int wm = wv >> 2, wn = wv & 3;
  const int lo = l & 15, kq = l >> 4;

  auto SA = [&](int kt, int h) {   // h=0 -> A-L, h=1 -> A-H
#pragma unroll
    for (int j = 0; j < 2; ++j) {
      const int p = j * 512 + tid;
      const int r = p >> 3, sl = p & 7;
      const int grow = m0 + h * 64 + (r & 63) + (r >> 6) * 128;
      gload16(A + (size_t)grow * 1024 + (kt << 6) + ((sl ^ (r & 7)) << 3),
              sh + (kt & 1) * 32768 + h * 8192 + p * 8);
    }
  };
  auto SB = [&](int kt, int h) {   // h=0 -> B-L, h=1 -> B-H
#pragma unroll
    for (int j = 0; j < 2; ++j) {
      const int p = j * 512 + tid;
      const int r = p >> 3, sl = p & 7;
      const int grow = n0 + h * 32 + (r & 31) + (r >> 5) * 64;
      gload16(W + (size_t)grow * 1024 + (kt << 6) + ((sl ^ (r & 7)) << 3),
              sh + (kt & 1) * 32768 + 16384 + h * 8192 + p * 8);
    }
  };
  auto LDA = [&](int cur, int mh, int mi, int ks) -> bf16x8 {
    const int r = wm * 64 + mi * 16 + lo;
    return *(const bf16x8*)&sh[cur * 32768 + mh * 8192 + r * 64 + (((ks * 4 + kq) ^ (r & 7)) << 3)];
  };
  auto LDB = [&](int cur, int nh, int ni, int ks) -> bf16x8 {
    const int r = wn * 32 + ni * 16 + lo;
    return *(const bf16x8*)&sh[cur * 32768 + 16384 + nh * 8192 + r * 64 + (((ks * 4 + kq) ^ (r & 7)) << 3)];
  };

  // prologue: tile0 fully + tile1 {A-L,B-H,A-H}; B-L(1) comes from tile0 ph0.
  SA(0, 0); SB(0, 0); SB(0, 1); SA(0, 1);
  SA(1, 0); SB(1, 1); SA(1, 1);
  MEMFENCE;
  asm volatile("s_waitcnt vmcnt(6)" ::: "memory");
  __builtin_amdgcn_s_barrier();

  bf16x8 a[4][2], b[2][2], b2[2][2];
#pragma unroll 2
  for (int t = 0; t < 16; ++t) {
    const int cur = t & 1;
    // ---------- phase 0: C(m 0..3, n 0..1) ; reads A-L, B-L ----------
#pragma unroll
    for (int mi = 0; mi < 4; ++mi)
#pragma unroll
      for (int ks = 0; ks < 2; ++ks) a[mi][ks] = LDA(cur, 0, mi, ks);
#pragma unroll
    for (int ni = 0; ni < 2; ++ni)
#pragma unroll
      for (int ks = 0; ks < 2; ++ks) b[ni][ks] = LDB(cur, 0, ni, ks);
    if (t + 1 < 16) SB(t + 1, 0);
    MEMFENCE;
    asm volatile("s_waitcnt lgkmcnt(0)" ::: "memory");
    __builtin_amdgcn_sched_barrier(0);
    __builtin_amdgcn_s_setprio(1);
#pragma unroll
    for (int mi = 0; mi < 4; ++mi)
#pragma unroll
      for (int ni = 0; ni < 2; ++ni)
#pragma unroll
        for (int ks = 0; ks < 2; ++ks)
          acc[mi][ni] = mfma16(a[mi][ks], b[ni][ks], acc[mi][ni]);
    __builtin_amdgcn_s_setprio(0);
    MEMFENCE;
    __builtin_amdgcn_s_barrier();
    // ---------- phase 1: C(m 0..3, n 2..3) ; reads B-H ----------
#pragma unroll
    for (int ni = 0; ni < 2; ++ni)
#pragma unroll
      for (int ks = 0; ks < 2; ++ks) b2[ni][ks] = LDB(cur, 1, ni, ks);
    if (t + 2 < 16) SA(t + 2, 0);   // clobbers A-L(cur): fully read in ph0 (behind ph0 end-barrier)
    MEMFENCE;
    asm volatile("s_waitcnt lgkmcnt(0)" ::: "memory");
    __builtin_amdgcn_sched_barrier(0);
    __builtin_amdgcn_s_setprio(1);
#pragma unroll
    for (int mi = 0; mi < 4; ++mi)
#pragma unroll
      for (int ni = 0; ni < 2; ++ni)
#pragma unroll
        for (int ks = 0; ks < 2; ++ks)
          acc[mi][2 + ni] = mfma16(a[mi][ks], b2[ni][ks], acc[mi][2 + ni]);
    __builtin_amdgcn_s_setprio(0);
    MEMFENCE;
    __builtin_amdgcn_s_barrier();
    // ---------- phase 2: C(m 4..7, n 2..3) ; reads A-H (b2 in regs) ----------
#pragma unroll
    for (int mi = 0; mi < 4; ++mi)
#pragma unroll
      for (int ks = 0; ks < 2; ++ks) a[mi][ks] = LDA(cur, 1, mi, ks);
    if (t + 2 < 16) SB(t + 2, 1);   // clobbers B-H(cur): fully read in ph1
    MEMFENCE;
    asm volatile("s_waitcnt lgkmcnt(0)" ::: "memory");
    __builtin_amdgcn_sched_barrier(0);
    __builtin_amdgcn_s_setprio(1);
#pragma unroll
    for (int mi = 0; mi < 4; ++mi)
#pragma unroll
      for (int ni = 0; ni < 2; ++ni)
#pragma unroll
        for (int ks = 0; ks < 2; ++ks)
          acc[4 + mi][2 + ni] = mfma16(a[mi][ks], b2[ni][ks], acc[4 + mi][2 + ni]);
    __builtin_amdgcn_s_setprio(0);
    MEMFENCE;
    __builtin_amdgcn_s_barrier();
    // ---------- phase 3: C(m 4..7, n 0..1) ; reads B-L again (a in regs) ----------
#pragma unroll
    for (int ni = 0; ni < 2; ++ni)
#pragma unroll
      for (int ks = 0; ks < 2; ++ks) b[ni][ks] = LDB(cur, 0, ni, ks);
    if (t + 2 < 16) SA(t + 2, 1);   // clobbers A-H(cur): fully read in ph2
    MEMFENCE;
    asm volatile("s_waitcnt lgkmcnt(0)" ::: "memory");
    __builtin_amdgcn_sched_barrier(0);
    __builtin_amdgcn_s_setprio(1);
#pragma unroll
    for (int mi = 0; mi < 4; ++mi)
#pragma unroll
      for (int ni = 0; ni < 2; ++ni)
#pragma unroll
        for (int ks = 0; ks < 2; ++ks)
          acc[4 + mi][ni] = mfma16(a[mi][ks], b[ni][ks], acc[4 + mi][ni]);
    __builtin_amdgcn_s_setprio(0);
    if (t < 14) asm volatile("s_waitcnt vmcnt(6)" ::: "memory");
    else        asm volatile("s_waitcnt vmcnt(0)" ::: "memory");
    MEMFENCE;
    __builtin_amdgcn_s_barrier();
  }
}

// QKV: grid 768 = 3z x 64m x 4n, XCD-swizzled. z=0 Q rows; z=1 K rows + Kt; z=2 Vt.
__global__ __launch_bounds__(512, 2)
void gemm_qkv8_k(const __bf16* __restrict__ A,
                 const __bf16* __restrict__ Bq, const __bf16* __restrict__ Bk, const __bf16* __restrict__ Bv,
                 __bf16* __restrict__ Qo, __bf16* __restrict__ Ko,
                 __bf16* __restrict__ Kt, __bf16* __restrict__ Vt) {
  extern __shared__ __bf16 sh[];
  const int tid = threadIdx.x;
  const int flat = blockIdx.x;                     // [0,768), 768 = 8*96
  const int sf = (flat & 7) * 96 + (flat >> 3);
  const int z = sf >> 8;
  const int rem = sf & 255;
  const int m0 = (rem >> 2) * 256;
  const int n0 = (rem & 3) * 256;
  const __bf16* W = (z == 0) ? Bq : (z == 1) ? Bk : Bv;

  f32x4 acc[8][4] = {};
  kloop256(A, W, m0, n0, sh, tid, acc);

  const int l = tid & 63, wv = tid >> 6, wm = wv >> 2, wn = wv & 3;
  const int lo = l & 15, kq = l >> 4;

  // ---- row stores (Q / K) via LDS bounce: 2 passes over n-halves, [m][n] pitch 136 ----
  if (z <= 1) {
    __bf16* R = z ? Ko : Qo;
#pragma unroll
    for (int nh = 0; nh < 2; ++nh) {
      if ((wn >> 1) == nh) {
#pragma unroll
        for (int mi = 0; mi < 8; ++mi)
#pragma unroll
          for (int ni = 0; ni < 4; ++ni)
#pragma unroll
            for (int rr = 0; rr < 4; ++rr)
              sh[wm * 17408 + (mi * 16 + kq * 4 + rr) * 136 + (wn & 1) * 64 + ni * 16 + lo]
                  = (__bf16)acc[mi][ni][rr];
      }
      __syncthreads();
#pragma unroll
      for (int it = 0; it < 8; ++it) {
        const int idx = it * 512 + tid;
        const int rg = idx >> 11, mrow = (idx >> 4) & 127, sl = idx & 15;
        *(bf16x8*)(R + (size_t)(m0 + rg * 128 + mrow) * 1024 + n0 + nh * 128 + sl * 8)
            = *(const bf16x8*)&sh[rg * 17408 + mrow * 136 + sl * 8];
      }
      __syncthreads();
    }
  }
  // ---- transposed stores (Kt / Vt): 2 passes, [n][m] pitch 136 ----
  if (z >= 1) {
    __bf16* T = (z == 1) ? Kt : Vt;
    const int bb = m0 >> 12, s0v = m0 & 4095, h0 = n0 >> 7;
#pragma unroll
    for (int nh = 0; nh < 2; ++nh) {
      if ((wn >> 1) == nh) {
#pragma unroll
        for (int mi = 0; mi < 8; ++mi)
#pragma unroll
          for (int ni = 0; ni < 4; ++ni)
#pragma unroll
            for (int rr = 0; rr < 4; ++rr)
              sh[wm * 17408 + ((wn & 1) * 64 + ni * 16 + lo) * 136 + mi * 16 + kq * 4 + rr]
                  = (__bf16)acc[mi][ni][rr];
      }
      __syncthreads();
      const int hh = h0 + nh;
#pragma unroll
      for (int it = 0; it < 8; ++it) {
        const int idx = it * 512 + tid;
        const int rg = idx >> 11, dr = (idx >> 4) & 127, sl = idx & 15;
        *(bf16x8*)(T + ((size_t)((bb * 8 + hh) * 128 + dr)) * 4096 + s0v + rg * 128 + sl * 8)
            = *(const bf16x8*)&sh[rg * 17408 + dr * 136 + sl * 8];
      }
      __syncthreads();
    }
  }
}

// output GEMM (f32 out): grid 256 = 64m x 4n, XCD-swizzled
__global__ __launch_bounds__(512, 2)
void gemm_out8_k(const __bf16* __restrict__ A, const __bf16* __restrict__ W,
                 float* __restrict__ Co) {
  extern __shared__ __bf16 sh[];
  const int tid = threadIdx.x;
  const int flat = blockIdx.x;                     // [0,256)
  const int sf = (flat & 7) * 32 + (flat >> 3);
  const int m0 = (sf >> 2) * 256;
  const int n0 = (sf & 3) * 256;

  f32x4 acc[8][4] = {};
  kloop256(A, W, m0, n0, sh, tid, acc);

  const int l = tid & 63, wv = tid >> 6, wm = wv >> 2, wn = wv & 3;
  const int lo = l & 15, kq = l >> 4;
#pragma unroll
  for (int mi = 0; mi < 8; ++mi)
#pragma unroll
    for (int ni = 0; ni < 4; ++ni)
#pragma unroll
      for (int rr = 0; rr < 4; ++rr)
        Co[(size_t)(m0 + wm * 128 + mi * 16 + kq * 4 + rr) * 1024 + n0 + wn * 64 + ni * 16 + lo]
            = acc[mi][ni][rr];
}

// in-place exclusive prefix of zc over chunks
__global__ __launch_bounds__(128)
void z2_k(float* __restrict__ zc) {
  const int bh = blockIdx.x;
  const int d = threadIdx.x;
  float run = 0.0f;
  for (int cc = 0; cc < 64; ++cc) {
    float* p = zc + (size_t)(bh * 64 + cc) * 128 + d;
    const float old = *p;
    *p = run;
    run += old;
  }
}

// ---------------- pass A: per-chunk S_T[e][d] = sum_t V[t,e]*K[t,d]; also zc[bh][c][d] ----------------
__global__ __launch_bounds__(256)
void passA_k(const __bf16* __restrict__ Kt, const __bf16* __restrict__ Vt,
             __bf16* __restrict__ Sc, float* __restrict__ zc) {
  const int c = blockIdx.x, bh = blockIdx.y;
  const int tid = threadIdx.x, l = tid & 63, w = tid >> 6;
  const int wr = (w >> 1) * 64, wc = (w & 1) * 64;
  const int lr = l & 15, lk = (l >> 4) * 8;
  f32x4 acc[4][4] = {};
  float zac[4] = {0.0f, 0.0f, 0.0f, 0.0f};
#pragma unroll
  for (int kk = 0; kk < 2; ++kk) {
    const int t = c * 64 + kk * 32 + lk;
    bf16x8 av[4], bk[4];
#pragma unroll
    for (int mt = 0; mt < 4; ++mt)
      av[mt] = *(const bf16x8*)(Vt + ((size_t)(bh * 128 + wr + mt * 16 + lr)) * 4096 + t);
#pragma unroll
    for (int nt = 0; nt < 4; ++nt) {
      bk[nt] = *(const bf16x8*)(Kt + ((size_t)(bh * 128 + wc + nt * 16 + lr)) * 4096 + t);
#pragma unroll
      for (int e = 0; e < 8; ++e) zac[nt] += (float)bk[nt][e];
    }
#pragma unroll
    for (int mt = 0; mt < 4; ++mt)
#pragma unroll
      for (int nt = 0; nt < 4; ++nt)
        acc[mt][nt] = mfma16(av[mt], bk[nt], acc[mt][nt]);
  }
  // z chunk-sum: reduce across the 4 lk-groups (lanes lr, lr+16, lr+32, lr+48)
#pragma unroll
  for (int nt = 0; nt < 4; ++nt) {
    zac[nt] += __shfl_xor(zac[nt], 16);
    zac[nt] += __shfl_xor(zac[nt], 32);
  }
  if (w < 2 && l < 16) {
#pragma unroll
    for (int nt = 0; nt < 4; ++nt)
      zc[(size_t)(bh * 64 + c) * 128 + wc + nt * 16 + lr] = zac[nt];
  }
  const size_t sbase = ((size_t)(bh * 64 + c)) << 14;
#pragma unroll
  for (int mt = 0; mt < 4; ++mt)
#pragma unroll
    for (int r = 0; r < 4; ++r) {
      const int e = wr + mt * 16 + (l >> 4) * 4 + r;
#pragma unroll
      for (int nt = 0; nt < 4; ++nt) {
        const int d = wc + nt * 16 + lr;
        Sc[sbase + (size_t)e * 128 + d] = (__bf16)acc[mt][nt][r];
      }
    }
}

// ---------------- pass B: in-place exclusive prefix of Sc over chunks ----------------
__global__ __launch_bounds__(256)
void passB_k(__bf16* __restrict__ Sc) {
  const int bh = blockIdx.y;
  const int idx = blockIdx.x * 256 + threadIdx.x;
  float run = 0.0f;
  for (int cc = 0; cc < 64; ++cc) {
    __bf16* p = Sc + (((size_t)(bh * 64 + cc)) << 14) + idx;
    const float old = (float)*p;
    *p = (__bf16)run;
    run += old;
  }
}

// ---------------- pass C: outputs + denom + rmsnorm ----------------
__global__ __launch_bounds__(256)
void passC_k(const __bf16* __restrict__ Q, const __bf16* __restrict__ K,
             const __bf16* __restrict__ Vt, const __bf16* __restrict__ Sp,
             const float* __restrict__ zp, const float* __restrict__ nw,
             __bf16* __restrict__ O) {
  alignas(16) __shared__ __bf16 ScL[64 * 72];
  alignas(16) __shared__ float OL[64 * 132];
  alignas(16) __shared__ float zPL[128];
  alignas(16) __shared__ float nwL[128];
  alignas(16) __shared__ float dnL[64];
  const int c = blockIdx.x, bh = blockIdx.y;
  const int bb = bh >> 3, hh = bh & 7;
  const int tid = threadIdx.x, l = tid & 63, wv = tid >> 6;
  const int lr = l & 15, lk = (l >> 4) * 8;
  if (tid < 128) zPL[tid] = zp[(size_t)(bh * 64 + c) * 128 + tid];
  else nwL[tid - 128] = nw[tid - 128];

  const size_t qbase = ((size_t)(bb * 4096 + c * 64)) * 1024 + hh * 128;
  const size_t sbase = ((size_t)(bh * 64 + c)) << 14;

  f32x4 accO[4][2] = {};
  f32x4 accS[4] = {};
#pragma unroll
  for (int kk = 0; kk < 4; ++kk) {
    const int dof = kk * 32 + lk;
    bf16x8 aQ[4], bS[2], bK;
#pragma unroll
    for (int mt = 0; mt < 4; ++mt)
      aQ[mt] = *(const bf16x8*)(Q + qbase + (size_t)(mt * 16 + lr) * 1024 + dof);
#pragma unroll
    for (int nt = 0; nt < 2; ++nt)
      bS[nt] = *(const bf16x8*)(Sp + sbase + (size_t)(wv * 32 + nt * 16 + lr) * 128 + dof);
    bK = *(const bf16x8*)(K + qbase + (size_t)(wv * 16 + lr) * 1024 + dof);
#pragma unroll
    for (int mt = 0; mt < 4; ++mt) {
      accS[mt] = mfma16(aQ[mt], bK, accS[mt]);
#pragma unroll
      for (int nt = 0; nt < 2; ++nt)
        accO[mt][nt] = mfma16(aQ[mt], bS[nt], accO[mt][nt]);
    }
  }
  // masked scores -> LDS (bf16)
#pragma unroll
  for (int mt = 0; mt < 4; ++mt)
#pragma unroll
    for (int r = 0; r < 4; ++r) {
      const int srow = mt * 16 + (l >> 4) * 4 + r;
      const int tcol = wv * 16 + lr;
      ScL[srow * 72 + tcol] = (__bf16)((tcol <= srow) ? accS[mt][r] : 0.0f);
    }
  __syncthreads();
  // intra: acc += scores @ V   (B-operand = Vt rows)
#pragma unroll
  for (int kk2 = 0; kk2 < 2; ++kk2) {
    const int tof = kk2 * 32 + lk;
    bf16x8 aS[4], bV[2];
#pragma unroll
    for (int mt = 0; mt < 4; ++mt) aS[mt] = *(const bf16x8*)&ScL[(mt * 16 + lr) * 72 + tof];
#pragma unroll
    for (int nt = 0; nt < 2; ++nt)
      bV[nt] = *(const bf16x8*)(Vt + ((size_t)(bh * 128 + wv * 32 + nt * 16 + lr)) * 4096 + c * 64 + tof);
#pragma unroll
    for (int mt = 0; mt < 4; ++mt)
#pragma unroll
      for (int nt = 0; nt < 2; ++nt)
        accO[mt][nt] = mfma16(aS[mt], bV[nt], accO[mt][nt]);
  }
  // denom[s] = max(|q.z_prev + rowsum(masked scores)|, 1) — all 256 threads, 4 lanes/row
  {
    const int s = tid >> 2, grp = tid & 3;
    float rs = 0.0f;
#pragma unroll
    for (int t = 0; t < 16; ++t) rs += (float)ScL[s * 72 + grp * 16 + t];
    float qz = 0.0f;
    const __bf16* qrow = Q + qbase + (size_t)s * 1024 + grp * 32;
#pragma unroll
    for (int j = 0; j < 4; ++j) {
      const bf16x8 q8 = *(const bf16x8*)(qrow + j * 8);
#pragma unroll
      for (int i = 0; i < 8; ++i) qz += (float)q8[i] * zPL[grp * 32 + j * 8 + i];
    }
    float v = rs + qz;
    v += __shfl_xor(v, 1);
    v += __shfl_xor(v, 2);
    if (grp == 0) dnL[s] = fmaxf(fabsf(v), 1.0f);
  }
  __syncthreads();
#pragma unroll
  for (int mt = 0; mt < 4; ++mt)
#pragma unroll
    for (int r = 0; r < 4; ++r) {
      const int row = mt * 16 + (l >> 4) * 4 + r;
#pragma unroll
      for (int nt = 0; nt < 2; ++nt) {
        const int col = wv * 32 + nt * 16 + lr;
        OL[row * 132 + col] = accO[mt][nt][r] / dnL[row];
      }
    }
  __syncthreads();
  // rmsnorm over D=128 + store bf16
  const int s = tid >> 2, e0 = (tid & 3) * 32;
  float ss = 0.0f;
  for (int i = 0; i < 32; ++i) { const float v = OL[s * 132 + e0 + i]; ss += v * v; }
  ss += __shfl_xor(ss, 1);
  ss += __shfl_xor(ss, 2);
  const float scale = rsqrtf(ss * (1.0f / 128.0f) + 1e-5f);
  __bf16* orow = O + qbase + (size_t)s * 1024 + e0;
#pragma unroll
  for (int i8 = 0; i8 < 4; ++i8) {
    bf16x8 ov;
#pragma unroll
    for (int j = 0; j < 8; ++j) {
      const int e = e0 + i8 * 8 + j;
      ov[j] = (__bf16)(OL[s * 132 + e] * scale * nwL[e]);
    }
    *(bf16x8*)(orow + i8 * 8) = ov;
  }
}

extern "C" void kernel_launch(void* const* d_in, const int* in_sizes, int n_in,
                              void* d_out, int out_size, void* d_ws, size_t ws_size,
                              hipStream_t stream) {
  (void)in_sizes; (void)n_in; (void)out_size; (void)ws_size;
  const float* hid = (const float*)d_in[0];
  const float* Wq  = (const float*)d_in[1];
  const float* Wk  = (const float*)d_in[2];
  const float* Wv  = (const float*)d_in[3];
  const float* Wo  = (const float*)d_in[4];
  const float* nw  = (const float*)d_in[5];

  char* ws = (char*)d_ws;
  size_t off = 0;
  auto nxt = [&](size_t bytes) -> char* {
    char* p = ws + off;
    off += (bytes + 255) & ~(size_t)255;
    return p;
  };
  __bf16* hA  = (__bf16*)nxt(33554432);   // hidden bf16 [16384][1024]; reused as Ob after gemm_qkv
  __bf16* wqB = (__bf16*)nxt(2097152);
  __bf16* wkB = (__bf16*)nxt(2097152);
  __bf16* wvB = (__bf16*)nxt(2097152);
  __bf16* woB = (__bf16*)nxt(2097152);
  __bf16* Qb  = (__bf16*)nxt(33554432);   // Q rows [16384][1024]
  __bf16* Kb  = (__bf16*)nxt(33554432);   // K rows
  __bf16* Ktb = (__bf16*)nxt(33554432);   // K^T [bh][d][s]
  __bf16* Vtb = (__bf16*)nxt(33554432);   // V^T [bh][e][s]
  __bf16* Scb = (__bf16*)nxt(67108864);   // chunk states -> exclusive prefix [bh][c][e][d]
  float*  zcb = (float*)nxt(1048576);     // chunk z sums -> exclusive prefix [bh][c][d]
  __bf16* Ob  = hA;                       // alias: hA dead after gemm_qkv8_k

  cast8_k<<<8192, 256, 0, stream>>>(hid, hA);
  castw_k<<<dim3(512, 4), 256, 0, stream>>>(Wq, Wk, Wv, Wo, wqB, wkB, wvB, woB);
  gemm_qkv8_k<<<768, 512, 131072, stream>>>(hA, wqB, wkB, wvB, Qb, Kb, Ktb, Vtb);
  passA_k<<<dim3(64, 32), 256, 0, stream>>>(Ktb, Vtb, Scb, zcb);
  passB_k<<<dim3(64, 32), 256, 0, stream>>>(Scb);
  z2_k<<<32, 128, 0, stream>>>(zcb);
  passC_k<<<dim3(64, 32), 256, 0, stream>>>(Qb, Kb, Vtb, Scb, zcb, nw, Ob);
  gemm_out8_k<<<256, 512, 131072, stream>>>(Ob, woB, (float*)d_out);
}